// Round 1
// baseline (1142.543 us; speedup 1.0000x reference)
//
#include <hip/hip_runtime.h>
#include <hip/hip_bf16.h>
#include <stdint.h>

#define ENC_B 8192
#define NFED  16384
#define INDIM 1024
#define LAT   512
#define SCALE (1.0f/512.0f)

typedef __attribute__((ext_vector_type(4))) float f32x4;
typedef __attribute__((ext_vector_type(8))) short short8;
typedef __attribute__((ext_vector_type(4))) short short4_t;

// f32 -> bf16, round-to-nearest-even (inputs are finite)
static __device__ __forceinline__ short f2bf(float x){
  union { float f; uint32_t u; } v; v.f = x;
  uint32_t r = v.u + 0x7FFFu + ((v.u >> 16) & 1u);
  return (short)(r >> 16);
}

// ---------------- kernel 1: domain_diff [1024][512] f32 -> ddT [512][1024] bf16 ----
__global__ void ddT_kernel(const float* __restrict__ dd, short* __restrict__ ddT){
  const int n = blockIdx.x;                 // 0..511
  for (int k = threadIdx.x; k < INDIM; k += 256)
    ddT[(size_t)n*INDIM + k] = f2bf(dd[(size_t)k*LAT + n]);
}

// ---------------- kernel 2: kv[16384][512] bf16 = X[16384][1024] @ dd ---------------
__global__ __launch_bounds__(256, 2) void kv_gemm_kernel(const float* __restrict__ X,
                                                         const short* __restrict__ ddT,
                                                         short* __restrict__ kv){
  __shared__ __align__(16) short As[128*40];   // [row][k] bf16, pad->80B rows
  __shared__ __align__(16) short Bs[128*40];   // [col][k] bf16 (from ddT)
  const int t = threadIdx.x;
  const int lane = t & 63, w = t >> 6;
  const int lr = lane & 15, lg = lane >> 4;
  const int m0 = (blockIdx.x >> 2) * 128;
  const int n0 = (blockIdx.x & 3) * 128;
  const int wm = (w >> 1) * 64, wn = (w & 1) * 64;
  f32x4 acc[4][4];
  #pragma unroll
  for (int i=0;i<4;++i)
    #pragma unroll
    for (int j=0;j<4;++j) acc[i][j] = (f32x4){0.f,0.f,0.f,0.f};

  for (int k0 = 0; k0 < INDIM; k0 += 32) {
    #pragma unroll
    for (int i = 0; i < 4; ++i) {               // A: 128x32 f32 -> bf16
      int idx = t + i*256;                       // 1024 float4s
      int row = idx >> 3, c4 = (idx & 7)*4;
      float4 v = *(const float4*)(X + (size_t)(m0+row)*INDIM + k0 + c4);
      short4_t s; s[0]=f2bf(v.x); s[1]=f2bf(v.y); s[2]=f2bf(v.z); s[3]=f2bf(v.w);
      *(short4_t*)(As + row*40 + c4) = s;
    }
    #pragma unroll
    for (int i = 0; i < 2; ++i) {               // B: 128x32 bf16 from ddT
      int idx = t + i*256;                       // 512 uint4s
      int row = idx >> 2, c8 = (idx & 3)*8;
      *(uint4*)(Bs + row*40 + c8) = *(const uint4*)(ddT + (size_t)(n0+row)*INDIM + k0 + c8);
    }
    __syncthreads();
    short8 a[4], b[4];
    #pragma unroll
    for (int i=0;i<4;++i) a[i] = *(short8*)(As + (wm + i*16 + lr)*40 + lg*8);
    #pragma unroll
    for (int i=0;i<4;++i) b[i] = *(short8*)(Bs + (wn + i*16 + lr)*40 + lg*8);
    #pragma unroll
    for (int i=0;i<4;++i)
      #pragma unroll
      for (int j=0;j<4;++j)
        acc[i][j] = __builtin_amdgcn_mfma_f32_16x16x32_bf16(a[i], b[j], acc[i][j], 0,0,0);
    __syncthreads();
  }
  #pragma unroll
  for (int i=0;i<4;++i)
    #pragma unroll
    for (int j=0;j<4;++j)
      #pragma unroll
      for (int r=0;r<4;++r)
        kv[(size_t)(m0 + wm + i*16 + lg*4 + r)*LAT + n0 + wn + j*16 + lr] = f2bf(acc[i][j][r]);
}

// ---------------- kernel 3: flash attention, Q=enc*(1/512), K=V=kv ------------------
// block: 256 thr (4 waves), BQ=32 rows, BN=32 keys/tile, 512 tiles, grid 256
// Ks swizzle: byte ^= ((row ^ row>>3)&7)<<4 ; Ps swizzle: byte ^= (row&3)<<4
__global__ __launch_bounds__(256, 1) void attn_kernel(const float* __restrict__ enc,
                                                      const short* __restrict__ kv,
                                                      float* __restrict__ out){
  __shared__ __align__(16) char lds[32*1024 + 32*36*4 + 32*32*2 + 32*4];
  float* Ss   = (float*)(lds + 32768);           // [32][36] f32
  short* Ps_b = (short*)(lds + 32768 + 4608);    // [32][32] bf16, swizzled
  float* resc = (float*)(lds + 32768 + 4608 + 2048); // [32]

  const int t = threadIdx.x;
  const int lane = t & 63, w = t >> 6;
  const int lr = lane & 15, lg = lane >> 4;
  const int q0 = blockIdx.x * 32;
  const int mt = w >> 1, kh = w & 1;

  // Q (wave rows mt*16..+16) into registers, scale folded (2^-9, exact in bf16)
  short8 qreg[16];
  {
    const float* qp = enc + (size_t)(q0 + mt*16 + lr)*LAT + lg*8;
    #pragma unroll
    for (int d0 = 0; d0 < 16; ++d0) {
      float4 v0 = *(const float4*)(qp + d0*32);
      float4 v1 = *(const float4*)(qp + d0*32 + 4);
      short8 s;
      s[0]=f2bf(v0.x*SCALE); s[1]=f2bf(v0.y*SCALE); s[2]=f2bf(v0.z*SCALE); s[3]=f2bf(v0.w*SCALE);
      s[4]=f2bf(v1.x*SCALE); s[5]=f2bf(v1.y*SCALE); s[6]=f2bf(v1.z*SCALE); s[7]=f2bf(v1.w*SCALE);
      qreg[d0] = s;
    }
  }

  const int srow = t >> 3, sj = t & 7;           // softmax: 8 threads per q-row
  float m_r = -1e30f, l_r = 0.0f;

  const int dcol0 = w * 128;                     // PV: wave owns d-slice of 128
  f32x4 oacc[2][8];
  #pragma unroll
  for (int i=0;i<2;++i)
    #pragma unroll
    for (int n=0;n<8;++n) oacc[i][n] = (f32x4){0.f,0.f,0.f,0.f};

  for (int n0 = 0; n0 < NFED; n0 += 32) {
    // ---- stage KV tile (32x512 bf16) into Ks, swizzled ----
    #pragma unroll
    for (int i = 0; i < 8; ++i) {
      int idx = t + i*256;                        // 2048 uint4s
      int row = idx >> 6, c8 = (idx & 63) * 8;
      uint32_t off = (uint32_t)(row*1024) + (uint32_t)((c8*2) ^ (((row ^ (row>>3)) & 7) << 4));
      *(uint4*)(lds + off) = *(const uint4*)(kv + (size_t)(n0+row)*LAT + c8);
    }
    __syncthreads();

    // ---- QK^T: wave computes S[mt*16..+16][kh*16..+16] over full d=512 ----
    {
      f32x4 sacc = (f32x4){0.f,0.f,0.f,0.f};
      const int key = kh*16 + lr;
      const uint32_t swz = ((uint32_t)((key ^ (key>>3)) & 7)) << 4;
      #pragma unroll
      for (int d0 = 0; d0 < 16; ++d0) {
        uint32_t off = (uint32_t)(key*1024) + (uint32_t)((d0*64 + lg*16) ^ swz);
        short8 b = *(short8*)(lds + off);
        sacc = __builtin_amdgcn_mfma_f32_16x16x32_bf16(qreg[d0], b, sacc, 0,0,0);
      }
      #pragma unroll
      for (int r=0;r<4;++r)
        Ss[(mt*16 + lg*4 + r)*36 + kh*16 + lr] = sacc[r];
    }
    __syncthreads();

    // ---- online softmax ----
    {
      float4 sv = *(const float4*)(Ss + srow*36 + sj*4);
      float tmax = fmaxf(fmaxf(sv.x, sv.y), fmaxf(sv.z, sv.w));
      #pragma unroll
      for (int d=1; d<8; d<<=1) tmax = fmaxf(tmax, __shfl_xor(tmax, d, 64));
      float newm = fmaxf(m_r, tmax);
      float alpha = __expf(m_r - newm);
      float p0 = __expf(sv.x - newm), p1 = __expf(sv.y - newm),
            p2 = __expf(sv.z - newm), p3 = __expf(sv.w - newm);
      float psum = (p0+p1)+(p2+p3);
      #pragma unroll
      for (int d=1; d<8; d<<=1) psum += __shfl_xor(psum, d, 64);
      l_r = l_r * alpha + psum;
      m_r = newm;
      if (sj == 0) resc[srow] = alpha;
      short4_t pb; pb[0]=f2bf(p0); pb[1]=f2bf(p1); pb[2]=f2bf(p2); pb[3]=f2bf(p3);
      uint32_t poff = (uint32_t)(srow*64) + (uint32_t)((sj*8) ^ ((srow & 3) << 4));
      *(short4_t*)((char*)Ps_b + poff) = pb;
    }
    __syncthreads();

    // ---- PV: O[32 x 128-slice] += P(32x32) @ V(32x128-slice), V = Ks ----
    {
      #pragma unroll
      for (int i=0;i<2;++i)
        #pragma unroll
        for (int r=0;r<4;++r) {
          float f = resc[i*16 + lg*4 + r];
          #pragma unroll
          for (int n=0;n<8;++n) oacc[i][n][r] *= f;
        }
      short8 pa[2];
      #pragma unroll
      for (int i=0;i<2;++i) {
        int prow = i*16 + lr;
        uint32_t off = (uint32_t)(prow*64) + (uint32_t)((lg*16) ^ ((prow & 3) << 4));
        pa[i] = *(short8*)((char*)Ps_b + off);
      }
      #pragma unroll
      for (int n=0;n<8;++n) {
        const int dcol = dcol0 + n*16 + lr;
        short8 vb;
        #pragma unroll
        for (int j=0;j<8;++j) {
          int key = lg*8 + j;
          uint32_t off = (uint32_t)(key*1024) + (uint32_t)((dcol*2) ^ (((key ^ (key>>3)) & 7) << 4));
          vb[j] = *(const short*)(lds + off);
        }
        oacc[0][n] = __builtin_amdgcn_mfma_f32_16x16x32_bf16(pa[0], vb, oacc[0][n], 0,0,0);
        oacc[1][n] = __builtin_amdgcn_mfma_f32_16x16x32_bf16(pa[1], vb, oacc[1][n], 0,0,0);
      }
    }
    __syncthreads();
  }

  // ---- epilogue: normalize by l and store f32 ----
  if (sj == 0) resc[srow] = 1.0f / l_r;
  __syncthreads();
  #pragma unroll
  for (int i=0;i<2;++i)
    #pragma unroll
    for (int r=0;r<4;++r) {
      float linv = resc[i*16 + lg*4 + r];
      int row = q0 + i*16 + lg*4 + r;
      #pragma unroll
      for (int n=0;n<8;++n)
        out[(size_t)row*LAT + dcol0 + n*16 + lr] = oacc[i][n][r] * linv;
    }
}

extern "C" void kernel_launch(void* const* d_in, const int* in_sizes, int n_in,
                              void* d_out, int out_size, void* d_ws, size_t ws_size,
                              hipStream_t stream) {
  const float* enc = (const float*)d_in[0];   // 8192 x 512
  const float* X   = (const float*)d_in[1];   // 16384 x 1024
  const float* dd  = (const float*)d_in[2];   // 1024 x 512
  float* out = (float*)d_out;                  // 8192 x 512 f32

  short* kv  = (short*)d_ws;                                   // 16 MB bf16
  short* ddT = (short*)((char*)d_ws + (size_t)NFED*LAT*2);     // 1 MB bf16

  ddT_kernel<<<LAT, 256, 0, stream>>>(dd, ddT);
  kv_gemm_kernel<<<(NFED/128)*(LAT/128), 256, 0, stream>>>(X, ddT, kv);
  attn_kernel<<<ENC_B/32, 256, 0, stream>>>(enc, kv, out);
}